// Round 1
// baseline (2199.852 us; speedup 1.0000x reference)
//
#include <hip/hip_runtime.h>
#include <math.h>

// ---------------------------------------------------------------------------
// GCN 5-layer forward. Plan:
//   1. Build CSR by dst (count -> exclusive scan -> fill) once per call.
//   2. dinv[v] = 1/sqrt(indeg[v]+1)
//   3. Per layer: h = x@W (LDS-staged weight GEMM, fp32 vector ALU),
//      then agg[v] = relu(dinv[v]*sum_{e->v} dinv[src]*h[src] + h[v]*dinv^2 + b)
//   4. Final linear N x 64 -> N x 1.
// ---------------------------------------------------------------------------

static inline int cdiv(int a, int b) { return (a + b - 1) / b; }

__global__ void zero_i32(int* __restrict__ p, int n) {
    int i = blockIdx.x * 256 + threadIdx.x;
    if (i < n) p[i] = 0;
}

__global__ void count_kernel(const int* __restrict__ dst, int* __restrict__ cnt, int E) {
    int e = blockIdx.x * 256 + threadIdx.x;
    if (e < E) atomicAdd(&cnt[dst[e]], 1);
}

// Inclusive scan per 256-block; writes inclusive partials to off, block totals to bsum.
__global__ void scan1(const int* __restrict__ cnt, int* __restrict__ off,
                      int* __restrict__ bsum, int n) {
    __shared__ int sm[256];
    int i = blockIdx.x * 256 + threadIdx.x;
    int v = (i < n) ? cnt[i] : 0;
    sm[threadIdx.x] = v;
    __syncthreads();
    for (int ofs = 1; ofs < 256; ofs <<= 1) {
        int t = (threadIdx.x >= (unsigned)ofs) ? sm[threadIdx.x - ofs] : 0;
        __syncthreads();
        sm[threadIdx.x] += t;
        __syncthreads();
    }
    if (i < n) off[i] = sm[threadIdx.x];
    if (threadIdx.x == 255) bsum[blockIdx.x] = sm[255];
}

// Exclusive scan of block sums (nb <= 512), one block of 512 threads.
__global__ void scan2(const int* __restrict__ bsum, int* __restrict__ bpre,
                      int nb, int* __restrict__ off, int N, int E) {
    __shared__ int sm[512];
    int t = threadIdx.x;
    sm[t] = (t < nb) ? bsum[t] : 0;
    __syncthreads();
    for (int ofs = 1; ofs < 512; ofs <<= 1) {
        int v = (t >= ofs) ? sm[t - ofs] : 0;
        __syncthreads();
        sm[t] += v;
        __syncthreads();
    }
    if (t < nb) bpre[t] = sm[t] - bsum[t];  // exclusive prefix
    if (t == 0) off[N] = E;                 // total = E (every edge has a dst)
}

// off[i] := exclusive = inclusive - cnt + blockPrefix ; also zero cursor.
__global__ void scan3(const int* __restrict__ cnt, const int* __restrict__ bpre,
                      int* __restrict__ off, int* __restrict__ cursor, int n) {
    int i = blockIdx.x * 256 + threadIdx.x;
    if (i < n) {
        off[i] = off[i] - cnt[i] + bpre[blockIdx.x];
        cursor[i] = 0;
    }
}

__global__ void fill_kernel(const int* __restrict__ src, const int* __restrict__ dst,
                            const int* __restrict__ off, int* __restrict__ cursor,
                            int* __restrict__ csr, int E) {
    int e = blockIdx.x * 256 + threadIdx.x;
    if (e < E) {
        int d = dst[e];
        int p = atomicAdd(&cursor[d], 1);
        csr[off[d] + p] = src[e];
    }
}

__global__ void dinv_kernel(const int* __restrict__ cnt, float* __restrict__ dinv, int n) {
    int i = blockIdx.x * 256 + threadIdx.x;
    if (i < n) dinv[i] = 1.0f / sqrtf((float)cnt[i] + 1.0f);
}

// ---------------------------------------------------------------------------
// GEMM: h[N,F] = x[N,K] @ W[K,F]. Weight fully staged in LDS. Each thread owns
// 2 rows x 4 consecutive cols (reuses each LDS weight read for 2 rows).
// ---------------------------------------------------------------------------
template <int K, int F>
__global__ __launch_bounds__(256) void gemm_kernel(const float* __restrict__ x,
                                                   const float* __restrict__ W,
                                                   float* __restrict__ h, int n) {
    constexpr int TPR = F / 4;       // threads per row
    constexpr int RG = 256 / TPR;    // row groups per block
    constexpr int ROWS = RG * 2;     // rows per block
    __shared__ float Ws[K * F];
    for (int i = threadIdx.x; i < K * F; i += 256) Ws[i] = W[i];
    __syncthreads();

    int tid = threadIdx.x;
    int cb = (tid % TPR) * 4;
    int rg = tid / TPR;
    int r0 = blockIdx.x * ROWS + rg * 2;
    int r1 = r0 + 1;
    if (r0 >= n) return;
    bool v1 = (r1 < n);

    const float* x0 = x + (size_t)r0 * K;
    const float* x1 = x + (size_t)r1 * K;
    float a0 = 0.f, a1 = 0.f, a2 = 0.f, a3 = 0.f;
    float b0 = 0.f, b1 = 0.f, b2 = 0.f, b3 = 0.f;

    if constexpr (K % 4 == 0) {
        for (int k0 = 0; k0 < K; k0 += 4) {
            float4 xa = *reinterpret_cast<const float4*>(x0 + k0);
            float4 xb = v1 ? *reinterpret_cast<const float4*>(x1 + k0)
                           : float4{0.f, 0.f, 0.f, 0.f};
            float xav[4] = {xa.x, xa.y, xa.z, xa.w};
            float xbv[4] = {xb.x, xb.y, xb.z, xb.w};
#pragma unroll
            for (int kk = 0; kk < 4; kk++) {
                float4 w = *reinterpret_cast<const float4*>(&Ws[(k0 + kk) * F + cb]);
                float xa1 = xav[kk], xb1 = xbv[kk];
                a0 += xa1 * w.x; a1 += xa1 * w.y; a2 += xa1 * w.z; a3 += xa1 * w.w;
                b0 += xb1 * w.x; b1 += xb1 * w.y; b2 += xb1 * w.z; b3 += xb1 * w.w;
            }
        }
    } else {
        for (int k = 0; k < K; k++) {
            float xa1 = x0[k];
            float xb1 = v1 ? x1[k] : 0.f;
            float4 w = *reinterpret_cast<const float4*>(&Ws[k * F + cb]);
            a0 += xa1 * w.x; a1 += xa1 * w.y; a2 += xa1 * w.z; a3 += xa1 * w.w;
            b0 += xb1 * w.x; b1 += xb1 * w.y; b2 += xb1 * w.z; b3 += xb1 * w.w;
        }
    }
    *reinterpret_cast<float4*>(&h[(size_t)r0 * F + cb]) = float4{a0, a1, a2, a3};
    if (v1) *reinterpret_cast<float4*>(&h[(size_t)r1 * F + cb]) = float4{b0, b1, b2, b3};
}

// ---------------------------------------------------------------------------
// Aggregation: out[v] = relu(dinv[v]*sum_{s in CSR[v]} dinv[s]*h[s] +
//                            h[v]*dinv[v]^2 + bias)
// One sub-wave of L = min(F,64) lanes per node; CPL = F/L cols per lane.
// Edge indices + dinv[src] fetched coalesced per chunk, distributed via shfl.
// ---------------------------------------------------------------------------
template <int F>
__global__ __launch_bounds__(256) void agg_kernel(const float* __restrict__ h,
                                                  const int* __restrict__ off,
                                                  const int* __restrict__ csr,
                                                  const float* __restrict__ dinv,
                                                  const float* __restrict__ bias,
                                                  float* __restrict__ out, int n) {
    constexpr int L = (F < 64) ? F : 64;   // lanes per node
    constexpr int CPL = F / L;             // cols per lane (2 for F=128, else 1)
    constexpr int NPW = 64 / L;            // nodes per wave
    constexpr int NPB = 4 * NPW;           // nodes per 256-thread block

    int tid = threadIdx.x;
    int wave = tid >> 6;
    int lane = tid & 63;
    int sub = lane / L;
    int sl = lane % L;
    int v = blockIdx.x * NPB + wave * NPW + sub;
    if (v >= n) return;

    int start = off[v];
    int end = off[v + 1];
    int subbase = sub * L;

    float acc[CPL];
#pragma unroll
    for (int c = 0; c < CPL; c++) acc[c] = 0.f;

    for (int base = start; base < end; base += L) {
        int m = end - base;
        if (m > L) m = L;
        int idx = 0;
        float dvp = 0.f;
        if (sl < m) {
            idx = csr[base + sl];
            dvp = dinv[idx];
        }
        for (int i = 0; i < m; i++) {
            int s = __shfl(idx, subbase + i);
            float d = __shfl(dvp, subbase + i);
            if constexpr (CPL == 2) {
                float2 hh = *reinterpret_cast<const float2*>(h + (size_t)s * F + sl * 2);
                acc[0] += d * hh.x;
                acc[1] += d * hh.y;
            } else {
                acc[0] += d * h[(size_t)s * F + sl];
            }
        }
    }

    float dv = dinv[v];
    float dv2 = dv * dv;
    if constexpr (CPL == 2) {
        float2 hv = *reinterpret_cast<const float2*>(h + (size_t)v * F + sl * 2);
        float o0 = dv * acc[0] + hv.x * dv2 + bias[sl * 2 + 0];
        float o1 = dv * acc[1] + hv.y * dv2 + bias[sl * 2 + 1];
        float2 r;
        r.x = o0 > 0.f ? o0 : 0.f;
        r.y = o1 > 0.f ? o1 : 0.f;
        *reinterpret_cast<float2*>(out + (size_t)v * F + sl * 2) = r;
    } else {
        float hv = h[(size_t)v * F + sl];
        float o = dv * acc[0] + hv * dv2 + bias[sl];
        out[(size_t)v * F + sl] = o > 0.f ? o : 0.f;
    }
}

// Final linear: out[v] = x[v,:64] . Wl + bl
__global__ __launch_bounds__(256) void final_kernel(const float* __restrict__ x,
                                                    const float* __restrict__ Wl,
                                                    const float* __restrict__ bl,
                                                    float* __restrict__ out, int n) {
    __shared__ float w[64];
    if (threadIdx.x < 64) w[threadIdx.x] = Wl[threadIdx.x];
    __syncthreads();
    int i = blockIdx.x * 256 + threadIdx.x;
    if (i >= n) return;
    const float* r = x + (size_t)i * 64;
    float acc = 0.f;
#pragma unroll
    for (int k = 0; k < 64; k += 4) {
        float4 xv = *reinterpret_cast<const float4*>(r + k);
        acc += xv.x * w[k] + xv.y * w[k + 1] + xv.z * w[k + 2] + xv.w * w[k + 3];
    }
    out[i] = acc + bl[0];
}

extern "C" void kernel_launch(void* const* d_in, const int* in_sizes, int n_in,
                              void* d_out, int out_size, void* d_ws, size_t ws_size,
                              hipStream_t stream) {
    const float* x = (const float*)d_in[0];
    const int* ei = (const int*)d_in[1];
    const float* W1 = (const float*)d_in[3];
    const float* b1 = (const float*)d_in[4];
    const float* W2 = (const float*)d_in[5];
    const float* b2 = (const float*)d_in[6];
    const float* W3 = (const float*)d_in[7];
    const float* b3 = (const float*)d_in[8];
    const float* W4 = (const float*)d_in[9];
    const float* b4 = (const float*)d_in[10];
    const float* W5 = (const float*)d_in[11];
    const float* b5 = (const float*)d_in[12];
    const float* Wl = (const float*)d_in[13];
    const float* bl = (const float*)d_in[14];

    const int N = in_sizes[0] / 2;
    const int E = in_sizes[1] / 2;
    const int* src = ei;
    const int* dst = ei + E;

    // Workspace carve (256 B aligned).
    char* wp = (char*)d_ws;
    auto alloc = [&](size_t bytes) -> void* {
        void* p = wp;
        wp += ((bytes + 255) / 256) * 256;
        return p;
    };
    int* cnt = (int*)alloc((size_t)N * 4);
    int* off = (int*)alloc((size_t)(N + 1) * 4);
    int* cursor = (int*)alloc((size_t)N * 4);
    int* bsum = (int*)alloc(512 * 4);
    int* bpre = (int*)alloc(512 * 4);
    int* csr = (int*)alloc((size_t)E * 4);
    float* dinv = (float*)alloc((size_t)N * 4);
    float* bufA = (float*)alloc((size_t)N * 128 * 4);
    float* bufB = (float*)alloc((size_t)N * 128 * 4);

    const int gE = cdiv(E, 256);
    const int gN = cdiv(N, 256);
    const int nb = gN;  // scan1 block count (391 <= 512)

    // --- CSR build ---
    zero_i32<<<gN, 256, 0, stream>>>(cnt, N);
    count_kernel<<<gE, 256, 0, stream>>>(dst, cnt, E);
    scan1<<<nb, 256, 0, stream>>>(cnt, off, bsum, N);
    scan2<<<1, 512, 0, stream>>>(bsum, bpre, nb, off, N, E);
    scan3<<<nb, 256, 0, stream>>>(cnt, bpre, off, cursor, N);
    fill_kernel<<<gE, 256, 0, stream>>>(src, dst, off, cursor, csr, E);
    dinv_kernel<<<gN, 256, 0, stream>>>(cnt, dinv, N);

    // --- Layer 1: [N,2] @ [2,128] ---
    gemm_kernel<2, 128><<<cdiv(N, 16), 256, 0, stream>>>(x, W1, bufA, N);
    agg_kernel<128><<<cdiv(N, 4), 256, 0, stream>>>(bufA, off, csr, dinv, b1, bufB, N);
    // --- Layer 2: [N,128] @ [128,128] ---
    gemm_kernel<128, 128><<<cdiv(N, 16), 256, 0, stream>>>(bufB, W2, bufA, N);
    agg_kernel<128><<<cdiv(N, 4), 256, 0, stream>>>(bufA, off, csr, dinv, b2, bufB, N);
    // --- Layer 3: [N,128] @ [128,32] ---
    gemm_kernel<128, 32><<<cdiv(N, 64), 256, 0, stream>>>(bufB, W3, bufA, N);
    agg_kernel<32><<<cdiv(N, 8), 256, 0, stream>>>(bufA, off, csr, dinv, b3, bufB, N);
    // --- Layer 4: [N,32] @ [32,32] ---
    gemm_kernel<32, 32><<<cdiv(N, 64), 256, 0, stream>>>(bufB, W4, bufA, N);
    agg_kernel<32><<<cdiv(N, 8), 256, 0, stream>>>(bufA, off, csr, dinv, b4, bufB, N);
    // --- Layer 5: [N,32] @ [32,64] ---
    gemm_kernel<32, 64><<<cdiv(N, 32), 256, 0, stream>>>(bufB, W5, bufA, N);
    agg_kernel<64><<<cdiv(N, 4), 256, 0, stream>>>(bufA, off, csr, dinv, b5, bufB, N);
    // --- Final linear: [N,64] @ [64,1] ---
    final_kernel<<<gN, 256, 0, stream>>>(bufB, Wl, bl, (float*)d_out, N);
}

// Round 2
// 1128.930 us; speedup vs baseline: 1.9486x; 1.9486x over previous
//
#include <hip/hip_runtime.h>
#include <math.h>

// ---------------------------------------------------------------------------
// GCN 5-layer forward.
//   1. Build CSR by dst (count -> exclusive scan -> fill) once per call.
//   2. dinv[v] = 1/sqrt(indeg[v]+1)
//   3. Per layer: h = x@W (register-tiled fp32 GEMM, LDS-chunked),
//      then agg[v] = relu(dinv[v]*sum_{e->v} dinv[src]*h[src] + h[v]*dinv^2 + b)
//   4. Final linear N x 64 -> N x 1.
// R1 change: replace spilling GEMM (256 VGPR, 3.4 GB scratch traffic, 1130us)
// with 64-row register-tiled GEMM, K chunked by 16, x+W chunks in LDS.
// ---------------------------------------------------------------------------

static inline int cdiv(int a, int b) { return (a + b - 1) / b; }

__global__ void zero_i32(int* __restrict__ p, int n) {
    int i = blockIdx.x * 256 + threadIdx.x;
    if (i < n) p[i] = 0;
}

__global__ void count_kernel(const int* __restrict__ dst, int* __restrict__ cnt, int E) {
    int e = blockIdx.x * 256 + threadIdx.x;
    if (e < E) atomicAdd(&cnt[dst[e]], 1);
}

// Inclusive scan per 256-block; writes inclusive partials to off, block totals to bsum.
__global__ void scan1(const int* __restrict__ cnt, int* __restrict__ off,
                      int* __restrict__ bsum, int n) {
    __shared__ int sm[256];
    int i = blockIdx.x * 256 + threadIdx.x;
    int v = (i < n) ? cnt[i] : 0;
    sm[threadIdx.x] = v;
    __syncthreads();
    for (int ofs = 1; ofs < 256; ofs <<= 1) {
        int t = (threadIdx.x >= (unsigned)ofs) ? sm[threadIdx.x - ofs] : 0;
        __syncthreads();
        sm[threadIdx.x] += t;
        __syncthreads();
    }
    if (i < n) off[i] = sm[threadIdx.x];
    if (threadIdx.x == 255) bsum[blockIdx.x] = sm[255];
}

// Exclusive scan of block sums (nb <= 512), one block of 512 threads.
__global__ void scan2(const int* __restrict__ bsum, int* __restrict__ bpre,
                      int nb, int* __restrict__ off, int N, int E) {
    __shared__ int sm[512];
    int t = threadIdx.x;
    sm[t] = (t < nb) ? bsum[t] : 0;
    __syncthreads();
    for (int ofs = 1; ofs < 512; ofs <<= 1) {
        int v = (t >= ofs) ? sm[t - ofs] : 0;
        __syncthreads();
        sm[t] += v;
        __syncthreads();
    }
    if (t < nb) bpre[t] = sm[t] - bsum[t];  // exclusive prefix
    if (t == 0) off[N] = E;                 // total = E (every edge has a dst)
}

// off[i] := exclusive = inclusive - cnt + blockPrefix ; also zero cursor.
__global__ void scan3(const int* __restrict__ cnt, const int* __restrict__ bpre,
                      int* __restrict__ off, int* __restrict__ cursor, int n) {
    int i = blockIdx.x * 256 + threadIdx.x;
    if (i < n) {
        off[i] = off[i] - cnt[i] + bpre[blockIdx.x];
        cursor[i] = 0;
    }
}

__global__ void fill_kernel(const int* __restrict__ src, const int* __restrict__ dst,
                            const int* __restrict__ off, int* __restrict__ cursor,
                            int* __restrict__ csr, int E) {
    int e = blockIdx.x * 256 + threadIdx.x;
    if (e < E) {
        int d = dst[e];
        int p = atomicAdd(&cursor[d], 1);
        csr[off[d] + p] = src[e];
    }
}

__global__ void dinv_kernel(const int* __restrict__ cnt, float* __restrict__ dinv, int n) {
    int i = blockIdx.x * 256 + threadIdx.x;
    if (i < n) dinv[i] = 1.0f / sqrtf((float)cnt[i] + 1.0f);
}

// ---------------------------------------------------------------------------
// Register-tiled GEMM: h[N,F] = x[N,K] @ W[K,F], K % 16 == 0, F in {32,64,128}.
// Block: 256 threads, 64-row x F tile. K chunked by KC=16; x-chunk (64x16, 4KB)
// and W-chunk (16xF, <=8KB) staged in LDS each iteration. Each thread owns
// RPT rows x 4 cols of accumulators (<=32 VGPR) -> no spill by construction.
// ---------------------------------------------------------------------------
template <int K, int F>
__global__ __launch_bounds__(256) void gemm_tiled(const float* __restrict__ x,
                                                  const float* __restrict__ W,
                                                  float* __restrict__ h, int n) {
    constexpr int KC = 16;
    constexpr int ROWS = 64;
    constexpr int TPC = F / 4;          // threads across cols (each owns 4)
    constexpr int RT = 256 / TPC;       // thread-rows
    constexpr int RPT = ROWS / RT;      // rows per thread (8/4/2 for F=128/64/32)
    static_assert(K % KC == 0, "K must be a multiple of 16");

    __shared__ float Ws[KC * F];        // [kk][c]
    __shared__ float Xs[ROWS * KC];     // [r][kk]

    const int tid = threadIdx.x;
    const int cb = (tid % TPC) * 4;
    const int tr = tid / TPC;           // 0..RT-1
    const int row0 = blockIdx.x * ROWS;

    float acc[RPT][4];
#pragma unroll
    for (int r = 0; r < RPT; r++)
#pragma unroll
        for (int j = 0; j < 4; j++) acc[r][j] = 0.f;

    for (int k0 = 0; k0 < K; k0 += KC) {
        __syncthreads();  // protect LDS from previous chunk's readers
        // Stage x chunk: 64 rows x 16 cols = 256 float4s, one per thread.
        {
            int r = tid >> 2;
            int kk = (tid & 3) * 4;
            int gr = row0 + r;
            float4 v = (gr < n)
                ? *reinterpret_cast<const float4*>(x + (size_t)gr * K + k0 + kk)
                : float4{0.f, 0.f, 0.f, 0.f};
            *reinterpret_cast<float4*>(&Xs[r * KC + kk]) = v;
        }
        // Stage W chunk: KC x F floats = KC*F/4 float4s.
        for (int i = tid; i < KC * F / 4; i += 256) {
            *reinterpret_cast<float4*>(&Ws[i * 4]) =
                *reinterpret_cast<const float4*>(W + (size_t)k0 * F + i * 4);
        }
        __syncthreads();

#pragma unroll
        for (int kk4 = 0; kk4 < KC; kk4 += 4) {
            float4 xr[RPT];
#pragma unroll
            for (int r = 0; r < RPT; r++)
                xr[r] = *reinterpret_cast<const float4*>(&Xs[(tr * RPT + r) * KC + kk4]);
#pragma unroll
            for (int j = 0; j < 4; j++) {
                float4 w = *reinterpret_cast<const float4*>(&Ws[(kk4 + j) * F + cb]);
#pragma unroll
                for (int r = 0; r < RPT; r++) {
                    float xv = (j == 0) ? xr[r].x : (j == 1) ? xr[r].y
                             : (j == 2) ? xr[r].z : xr[r].w;
                    acc[r][0] += xv * w.x;
                    acc[r][1] += xv * w.y;
                    acc[r][2] += xv * w.z;
                    acc[r][3] += xv * w.w;
                }
            }
        }
    }

#pragma unroll
    for (int r = 0; r < RPT; r++) {
        int row = row0 + tr * RPT + r;
        if (row < n)
            *reinterpret_cast<float4*>(&h[(size_t)row * F + cb]) =
                float4{acc[r][0], acc[r][1], acc[r][2], acc[r][3]};
    }
}

// Simple GEMM for K=2 (layer 1): trivially register-light.
template <int K, int F>
__global__ __launch_bounds__(256) void gemm_small(const float* __restrict__ x,
                                                  const float* __restrict__ W,
                                                  float* __restrict__ h, int n) {
    constexpr int TPR = F / 4;       // threads per row
    constexpr int ROWS = 256 / TPR;  // rows per block
    __shared__ float Ws[K * F];
    for (int i = threadIdx.x; i < K * F; i += 256) Ws[i] = W[i];
    __syncthreads();

    int tid = threadIdx.x;
    int cb = (tid % TPR) * 4;
    int r = blockIdx.x * ROWS + tid / TPR;
    if (r >= n) return;

    const float* xr = x + (size_t)r * K;
    float a0 = 0.f, a1 = 0.f, a2 = 0.f, a3 = 0.f;
#pragma unroll
    for (int k = 0; k < K; k++) {
        float xv = xr[k];
        float4 w = *reinterpret_cast<const float4*>(&Ws[k * F + cb]);
        a0 += xv * w.x; a1 += xv * w.y; a2 += xv * w.z; a3 += xv * w.w;
    }
    *reinterpret_cast<float4*>(&h[(size_t)r * F + cb]) = float4{a0, a1, a2, a3};
}

// ---------------------------------------------------------------------------
// Aggregation: out[v] = relu(dinv[v]*sum_{s in CSR[v]} dinv[s]*h[s] +
//                            h[v]*dinv[v]^2 + bias)
// One sub-wave of L = min(F,64) lanes per node; CPL = F/L cols per lane.
// ---------------------------------------------------------------------------
template <int F>
__global__ __launch_bounds__(256) void agg_kernel(const float* __restrict__ h,
                                                  const int* __restrict__ off,
                                                  const int* __restrict__ csr,
                                                  const float* __restrict__ dinv,
                                                  const float* __restrict__ bias,
                                                  float* __restrict__ out, int n) {
    constexpr int L = (F < 64) ? F : 64;   // lanes per node
    constexpr int CPL = F / L;             // cols per lane (2 for F=128, else 1)
    constexpr int NPW = 64 / L;            // nodes per wave
    constexpr int NPB = 4 * NPW;           // nodes per 256-thread block

    int tid = threadIdx.x;
    int wave = tid >> 6;
    int lane = tid & 63;
    int sub = lane / L;
    int sl = lane % L;
    int v = blockIdx.x * NPB + wave * NPW + sub;
    if (v >= n) return;

    int start = off[v];
    int end = off[v + 1];
    int subbase = sub * L;

    float acc[CPL];
#pragma unroll
    for (int c = 0; c < CPL; c++) acc[c] = 0.f;

    for (int base = start; base < end; base += L) {
        int m = end - base;
        if (m > L) m = L;
        int idx = 0;
        float dvp = 0.f;
        if (sl < m) {
            idx = csr[base + sl];
            dvp = dinv[idx];
        }
        for (int i = 0; i < m; i++) {
            int s = __shfl(idx, subbase + i);
            float d = __shfl(dvp, subbase + i);
            if constexpr (CPL == 2) {
                float2 hh = *reinterpret_cast<const float2*>(h + (size_t)s * F + sl * 2);
                acc[0] += d * hh.x;
                acc[1] += d * hh.y;
            } else {
                acc[0] += d * h[(size_t)s * F + sl];
            }
        }
    }

    float dv = dinv[v];
    float dv2 = dv * dv;
    if constexpr (CPL == 2) {
        float2 hv = *reinterpret_cast<const float2*>(h + (size_t)v * F + sl * 2);
        float o0 = dv * acc[0] + hv.x * dv2 + bias[sl * 2 + 0];
        float o1 = dv * acc[1] + hv.y * dv2 + bias[sl * 2 + 1];
        float2 r;
        r.x = o0 > 0.f ? o0 : 0.f;
        r.y = o1 > 0.f ? o1 : 0.f;
        *reinterpret_cast<float2*>(out + (size_t)v * F + sl * 2) = r;
    } else {
        float hv = h[(size_t)v * F + sl];
        float o = dv * acc[0] + hv * dv2 + bias[sl];
        out[(size_t)v * F + sl] = o > 0.f ? o : 0.f;
    }
}

// Final linear: out[v] = x[v,:64] . Wl + bl
__global__ __launch_bounds__(256) void final_kernel(const float* __restrict__ x,
                                                    const float* __restrict__ Wl,
                                                    const float* __restrict__ bl,
                                                    float* __restrict__ out, int n) {
    __shared__ float w[64];
    if (threadIdx.x < 64) w[threadIdx.x] = Wl[threadIdx.x];
    __syncthreads();
    int i = blockIdx.x * 256 + threadIdx.x;
    if (i >= n) return;
    const float* r = x + (size_t)i * 64;
    float acc = 0.f;
#pragma unroll
    for (int k = 0; k < 64; k += 4) {
        float4 xv = *reinterpret_cast<const float4*>(r + k);
        acc += xv.x * w[k] + xv.y * w[k + 1] + xv.z * w[k + 2] + xv.w * w[k + 3];
    }
    out[i] = acc + bl[0];
}

extern "C" void kernel_launch(void* const* d_in, const int* in_sizes, int n_in,
                              void* d_out, int out_size, void* d_ws, size_t ws_size,
                              hipStream_t stream) {
    const float* x = (const float*)d_in[0];
    const int* ei = (const int*)d_in[1];
    const float* W1 = (const float*)d_in[3];
    const float* b1 = (const float*)d_in[4];
    const float* W2 = (const float*)d_in[5];
    const float* b2 = (const float*)d_in[6];
    const float* W3 = (const float*)d_in[7];
    const float* b3 = (const float*)d_in[8];
    const float* W4 = (const float*)d_in[9];
    const float* b4 = (const float*)d_in[10];
    const float* W5 = (const float*)d_in[11];
    const float* b5 = (const float*)d_in[12];
    const float* Wl = (const float*)d_in[13];
    const float* bl = (const float*)d_in[14];

    const int N = in_sizes[0] / 2;
    const int E = in_sizes[1] / 2;
    const int* src = ei;
    const int* dst = ei + E;

    // Workspace carve (256 B aligned).
    char* wp = (char*)d_ws;
    auto alloc = [&](size_t bytes) -> void* {
        void* p = wp;
        wp += ((bytes + 255) / 256) * 256;
        return p;
    };
    int* cnt = (int*)alloc((size_t)N * 4);
    int* off = (int*)alloc((size_t)(N + 1) * 4);
    int* cursor = (int*)alloc((size_t)N * 4);
    int* bsum = (int*)alloc(512 * 4);
    int* bpre = (int*)alloc(512 * 4);
    int* csr = (int*)alloc((size_t)E * 4);
    float* dinv = (float*)alloc((size_t)N * 4);
    float* bufA = (float*)alloc((size_t)N * 128 * 4);
    float* bufB = (float*)alloc((size_t)N * 128 * 4);

    const int gE = cdiv(E, 256);
    const int gN = cdiv(N, 256);
    const int nb = gN;  // scan1 block count (391 <= 512)
    const int gT = cdiv(N, 64);  // tiled-gemm grid

    // --- CSR build ---
    zero_i32<<<gN, 256, 0, stream>>>(cnt, N);
    count_kernel<<<gE, 256, 0, stream>>>(dst, cnt, E);
    scan1<<<nb, 256, 0, stream>>>(cnt, off, bsum, N);
    scan2<<<1, 512, 0, stream>>>(bsum, bpre, nb, off, N, E);
    scan3<<<nb, 256, 0, stream>>>(cnt, bpre, off, cursor, N);
    fill_kernel<<<gE, 256, 0, stream>>>(src, dst, off, cursor, csr, E);
    dinv_kernel<<<gN, 256, 0, stream>>>(cnt, dinv, N);

    // --- Layer 1: [N,2] @ [2,128] ---
    gemm_small<2, 128><<<cdiv(N, 8), 256, 0, stream>>>(x, W1, bufA, N);
    agg_kernel<128><<<cdiv(N, 4), 256, 0, stream>>>(bufA, off, csr, dinv, b1, bufB, N);
    // --- Layer 2: [N,128] @ [128,128] ---
    gemm_tiled<128, 128><<<gT, 256, 0, stream>>>(bufB, W2, bufA, N);
    agg_kernel<128><<<cdiv(N, 4), 256, 0, stream>>>(bufA, off, csr, dinv, b2, bufB, N);
    // --- Layer 3: [N,128] @ [128,32] ---
    gemm_tiled<128, 32><<<gT, 256, 0, stream>>>(bufB, W3, bufA, N);
    agg_kernel<32><<<cdiv(N, 8), 256, 0, stream>>>(bufA, off, csr, dinv, b3, bufB, N);
    // --- Layer 4: [N,32] @ [32,32] ---
    gemm_tiled<32, 32><<<gT, 256, 0, stream>>>(bufB, W4, bufA, N);
    agg_kernel<32><<<cdiv(N, 8), 256, 0, stream>>>(bufA, off, csr, dinv, b4, bufB, N);
    // --- Layer 5: [N,32] @ [32,64] ---
    gemm_tiled<32, 64><<<gT, 256, 0, stream>>>(bufB, W5, bufA, N);
    agg_kernel<64><<<cdiv(N, 4), 256, 0, stream>>>(bufA, off, csr, dinv, b5, bufB, N);
    // --- Final linear: [N,64] @ [64,1] ---
    final_kernel<<<gN, 256, 0, stream>>>(bufB, Wl, bl, (float*)d_out, N);
}

// Round 3
// 844.912 us; speedup vs baseline: 2.6036x; 1.3362x over previous
//
#include <hip/hip_runtime.h>
#include <math.h>

// ---------------------------------------------------------------------------
// GCN 5-layer forward.
//   1. Build CSR by dst (count -> exclusive scan -> fill) once per call.
//   2. dinv[v] = 1/sqrt(indeg[v]+1)
//   3. Per layer: h = x@W (register-tiled fp32 GEMM, LDS-chunked),
//      then agg[v] = relu(dinv[v]*sum_{e->v} dinv[src]*h[src] + h[v]*dinv^2 + b)
//   4. Final linear N x 64 -> N x 1.
// R1: replace spilling GEMM (256 VGPR, 3.4 GB scratch) with 64-row tiled GEMM.
// R2: compiler still spilled (256 VGPR, ~760 MB scratch on <128,32>) due to
//     full unroll of the K-chunk loop. Fix: __launch_bounds__(256,4) caps
//     VGPR at 128, #pragma unroll 1 on the chunk loop, pad Xs stride 16->20
//     floats to kill the 1.6M LDS bank conflicts.
// ---------------------------------------------------------------------------

static inline int cdiv(int a, int b) { return (a + b - 1) / b; }

__global__ void zero_i32(int* __restrict__ p, int n) {
    int i = blockIdx.x * 256 + threadIdx.x;
    if (i < n) p[i] = 0;
}

__global__ void count_kernel(const int* __restrict__ dst, int* __restrict__ cnt, int E) {
    int e = blockIdx.x * 256 + threadIdx.x;
    if (e < E) atomicAdd(&cnt[dst[e]], 1);
}

// Inclusive scan per 256-block; writes inclusive partials to off, block totals to bsum.
__global__ void scan1(const int* __restrict__ cnt, int* __restrict__ off,
                      int* __restrict__ bsum, int n) {
    __shared__ int sm[256];
    int i = blockIdx.x * 256 + threadIdx.x;
    int v = (i < n) ? cnt[i] : 0;
    sm[threadIdx.x] = v;
    __syncthreads();
    for (int ofs = 1; ofs < 256; ofs <<= 1) {
        int t = (threadIdx.x >= (unsigned)ofs) ? sm[threadIdx.x - ofs] : 0;
        __syncthreads();
        sm[threadIdx.x] += t;
        __syncthreads();
    }
    if (i < n) off[i] = sm[threadIdx.x];
    if (threadIdx.x == 255) bsum[blockIdx.x] = sm[255];
}

// Exclusive scan of block sums (nb <= 512), one block of 512 threads.
__global__ void scan2(const int* __restrict__ bsum, int* __restrict__ bpre,
                      int nb, int* __restrict__ off, int N, int E) {
    __shared__ int sm[512];
    int t = threadIdx.x;
    sm[t] = (t < nb) ? bsum[t] : 0;
    __syncthreads();
    for (int ofs = 1; ofs < 512; ofs <<= 1) {
        int v = (t >= ofs) ? sm[t - ofs] : 0;
        __syncthreads();
        sm[t] += v;
        __syncthreads();
    }
    if (t < nb) bpre[t] = sm[t] - bsum[t];  // exclusive prefix
    if (t == 0) off[N] = E;                 // total = E (every edge has a dst)
}

// off[i] := exclusive = inclusive - cnt + blockPrefix ; also zero cursor.
__global__ void scan3(const int* __restrict__ cnt, const int* __restrict__ bpre,
                      int* __restrict__ off, int* __restrict__ cursor, int n) {
    int i = blockIdx.x * 256 + threadIdx.x;
    if (i < n) {
        off[i] = off[i] - cnt[i] + bpre[blockIdx.x];
        cursor[i] = 0;
    }
}

__global__ void fill_kernel(const int* __restrict__ src, const int* __restrict__ dst,
                            const int* __restrict__ off, int* __restrict__ cursor,
                            int* __restrict__ csr, int E) {
    int e = blockIdx.x * 256 + threadIdx.x;
    if (e < E) {
        int d = dst[e];
        int p = atomicAdd(&cursor[d], 1);
        csr[off[d] + p] = src[e];
    }
}

__global__ void dinv_kernel(const int* __restrict__ cnt, float* __restrict__ dinv, int n) {
    int i = blockIdx.x * 256 + threadIdx.x;
    if (i < n) dinv[i] = 1.0f / sqrtf((float)cnt[i] + 1.0f);
}

// ---------------------------------------------------------------------------
// Register-tiled GEMM: h[N,F] = x[N,K] @ W[K,F], K % 16 == 0, F in {32,64,128}.
// Block: 256 threads, 64-row x F tile. K chunked by KC=16; x-chunk (64x20pad)
// and W-chunk (16xF) staged in LDS each iteration. Each thread owns RPT rows
// x 4 cols of accumulators. __launch_bounds__(256,4) caps VGPR at 128 (honest
// demand ~90 for F=128) so the scheduler cannot spill; unroll 1 on the chunk
// loop stops unroll-driven register greed.
// ---------------------------------------------------------------------------
template <int K, int F>
__global__ __launch_bounds__(256, 4) void gemm_tiled(const float* __restrict__ x,
                                                     const float* __restrict__ W,
                                                     float* __restrict__ h, int n) {
    constexpr int KC = 16;
    constexpr int KCP = 20;             // padded row stride (80 B, 16B-aligned)
    constexpr int ROWS = 64;
    constexpr int TPC = F / 4;          // threads across cols (each owns 4)
    constexpr int RT = 256 / TPC;       // thread-rows
    constexpr int RPT = ROWS / RT;      // rows per thread (8/4/2 for F=128/64/32)
    static_assert(K % KC == 0, "K must be a multiple of 16");

    __shared__ float Ws[KC * F];        // [kk][c]
    __shared__ float Xs[ROWS * KCP];    // [r][kk], padded

    const int tid = threadIdx.x;
    const int cb = (tid % TPC) * 4;
    const int tr = tid / TPC;           // 0..RT-1
    const int row0 = blockIdx.x * ROWS;

    float acc[RPT][4];
#pragma unroll
    for (int r = 0; r < RPT; r++)
#pragma unroll
        for (int j = 0; j < 4; j++) acc[r][j] = 0.f;

#pragma unroll 1
    for (int k0 = 0; k0 < K; k0 += KC) {
        __syncthreads();  // protect LDS from previous chunk's readers
        // Stage x chunk: 64 rows x 16 cols = 256 float4s, one per thread.
        {
            int r = tid >> 2;
            int kk = (tid & 3) * 4;
            int gr = row0 + r;
            float4 v = (gr < n)
                ? *reinterpret_cast<const float4*>(x + (size_t)gr * K + k0 + kk)
                : float4{0.f, 0.f, 0.f, 0.f};
            *reinterpret_cast<float4*>(&Xs[r * KCP + kk]) = v;
        }
        // Stage W chunk: KC x F floats = KC*F/4 float4s.
        for (int i = tid; i < KC * F / 4; i += 256) {
            *reinterpret_cast<float4*>(&Ws[i * 4]) =
                *reinterpret_cast<const float4*>(W + (size_t)k0 * F + i * 4);
        }
        __syncthreads();

#pragma unroll
        for (int kk4 = 0; kk4 < KC; kk4 += 4) {
            float4 xr[RPT];
#pragma unroll
            for (int r = 0; r < RPT; r++)
                xr[r] = *reinterpret_cast<const float4*>(&Xs[(tr * RPT + r) * KCP + kk4]);
#pragma unroll
            for (int j = 0; j < 4; j++) {
                float4 w = *reinterpret_cast<const float4*>(&Ws[(kk4 + j) * F + cb]);
#pragma unroll
                for (int r = 0; r < RPT; r++) {
                    float xv = (j == 0) ? xr[r].x : (j == 1) ? xr[r].y
                             : (j == 2) ? xr[r].z : xr[r].w;
                    acc[r][0] += xv * w.x;
                    acc[r][1] += xv * w.y;
                    acc[r][2] += xv * w.z;
                    acc[r][3] += xv * w.w;
                }
            }
        }
    }

#pragma unroll
    for (int r = 0; r < RPT; r++) {
        int row = row0 + tr * RPT + r;
        if (row < n)
            *reinterpret_cast<float4*>(&h[(size_t)row * F + cb]) =
                float4{acc[r][0], acc[r][1], acc[r][2], acc[r][3]};
    }
}

// Simple GEMM for K=2 (layer 1): trivially register-light.
template <int K, int F>
__global__ __launch_bounds__(256, 4) void gemm_small(const float* __restrict__ x,
                                                     const float* __restrict__ W,
                                                     float* __restrict__ h, int n) {
    constexpr int TPR = F / 4;       // threads per row
    constexpr int ROWS = 256 / TPR;  // rows per block
    __shared__ float Ws[K * F];
    for (int i = threadIdx.x; i < K * F; i += 256) Ws[i] = W[i];
    __syncthreads();

    int tid = threadIdx.x;
    int cb = (tid % TPR) * 4;
    int r = blockIdx.x * ROWS + tid / TPR;
    if (r >= n) return;

    const float* xr = x + (size_t)r * K;
    float a0 = 0.f, a1 = 0.f, a2 = 0.f, a3 = 0.f;
#pragma unroll
    for (int k = 0; k < K; k++) {
        float xv = xr[k];
        float4 w = *reinterpret_cast<const float4*>(&Ws[k * F + cb]);
        a0 += xv * w.x; a1 += xv * w.y; a2 += xv * w.z; a3 += xv * w.w;
    }
    *reinterpret_cast<float4*>(&h[(size_t)r * F + cb]) = float4{a0, a1, a2, a3};
}

// ---------------------------------------------------------------------------
// Aggregation: out[v] = relu(dinv[v]*sum_{s in CSR[v]} dinv[s]*h[s] +
//                            h[v]*dinv[v]^2 + bias)
// One sub-wave of L = min(F,64) lanes per node; CPL = F/L cols per lane.
// ---------------------------------------------------------------------------
template <int F>
__global__ __launch_bounds__(256) void agg_kernel(const float* __restrict__ h,
                                                  const int* __restrict__ off,
                                                  const int* __restrict__ csr,
                                                  const float* __restrict__ dinv,
                                                  const float* __restrict__ bias,
                                                  float* __restrict__ out, int n) {
    constexpr int L = (F < 64) ? F : 64;   // lanes per node
    constexpr int CPL = F / L;             // cols per lane (2 for F=128, else 1)
    constexpr int NPW = 64 / L;            // nodes per wave
    constexpr int NPB = 4 * NPW;           // nodes per 256-thread block

    int tid = threadIdx.x;
    int wave = tid >> 6;
    int lane = tid & 63;
    int sub = lane / L;
    int sl = lane % L;
    int v = blockIdx.x * NPB + wave * NPW + sub;
    if (v >= n) return;

    int start = off[v];
    int end = off[v + 1];
    int subbase = sub * L;

    float acc[CPL];
#pragma unroll
    for (int c = 0; c < CPL; c++) acc[c] = 0.f;

    for (int base = start; base < end; base += L) {
        int m = end - base;
        if (m > L) m = L;
        int idx = 0;
        float dvp = 0.f;
        if (sl < m) {
            idx = csr[base + sl];
            dvp = dinv[idx];
        }
        for (int i = 0; i < m; i++) {
            int s = __shfl(idx, subbase + i);
            float d = __shfl(dvp, subbase + i);
            if constexpr (CPL == 2) {
                float2 hh = *reinterpret_cast<const float2*>(h + (size_t)s * F + sl * 2);
                acc[0] += d * hh.x;
                acc[1] += d * hh.y;
            } else {
                acc[0] += d * h[(size_t)s * F + sl];
            }
        }
    }

    float dv = dinv[v];
    float dv2 = dv * dv;
    if constexpr (CPL == 2) {
        float2 hv = *reinterpret_cast<const float2*>(h + (size_t)v * F + sl * 2);
        float o0 = dv * acc[0] + hv.x * dv2 + bias[sl * 2 + 0];
        float o1 = dv * acc[1] + hv.y * dv2 + bias[sl * 2 + 1];
        float2 r;
        r.x = o0 > 0.f ? o0 : 0.f;
        r.y = o1 > 0.f ? o1 : 0.f;
        *reinterpret_cast<float2*>(out + (size_t)v * F + sl * 2) = r;
    } else {
        float hv = h[(size_t)v * F + sl];
        float o = dv * acc[0] + hv * dv2 + bias[sl];
        out[(size_t)v * F + sl] = o > 0.f ? o : 0.f;
    }
}

// Final linear: out[v] = x[v,:64] . Wl + bl
__global__ __launch_bounds__(256) void final_kernel(const float* __restrict__ x,
                                                    const float* __restrict__ Wl,
                                                    const float* __restrict__ bl,
                                                    float* __restrict__ out, int n) {
    __shared__ float w[64];
    if (threadIdx.x < 64) w[threadIdx.x] = Wl[threadIdx.x];
    __syncthreads();
    int i = blockIdx.x * 256 + threadIdx.x;
    if (i >= n) return;
    const float* r = x + (size_t)i * 64;
    float acc = 0.f;
#pragma unroll
    for (int k = 0; k < 64; k += 4) {
        float4 xv = *reinterpret_cast<const float4*>(r + k);
        acc += xv.x * w[k] + xv.y * w[k + 1] + xv.z * w[k + 2] + xv.w * w[k + 3];
    }
    out[i] = acc + bl[0];
}

extern "C" void kernel_launch(void* const* d_in, const int* in_sizes, int n_in,
                              void* d_out, int out_size, void* d_ws, size_t ws_size,
                              hipStream_t stream) {
    const float* x = (const float*)d_in[0];
    const int* ei = (const int*)d_in[1];
    const float* W1 = (const float*)d_in[3];
    const float* b1 = (const float*)d_in[4];
    const float* W2 = (const float*)d_in[5];
    const float* b2 = (const float*)d_in[6];
    const float* W3 = (const float*)d_in[7];
    const float* b3 = (const float*)d_in[8];
    const float* W4 = (const float*)d_in[9];
    const float* b4 = (const float*)d_in[10];
    const float* W5 = (const float*)d_in[11];
    const float* b5 = (const float*)d_in[12];
    const float* Wl = (const float*)d_in[13];
    const float* bl = (const float*)d_in[14];

    const int N = in_sizes[0] / 2;
    const int E = in_sizes[1] / 2;
    const int* src = ei;
    const int* dst = ei + E;

    // Workspace carve (256 B aligned).
    char* wp = (char*)d_ws;
    auto alloc = [&](size_t bytes) -> void* {
        void* p = wp;
        wp += ((bytes + 255) / 256) * 256;
        return p;
    };
    int* cnt = (int*)alloc((size_t)N * 4);
    int* off = (int*)alloc((size_t)(N + 1) * 4);
    int* cursor = (int*)alloc((size_t)N * 4);
    int* bsum = (int*)alloc(512 * 4);
    int* bpre = (int*)alloc(512 * 4);
    int* csr = (int*)alloc((size_t)E * 4);
    float* dinv = (float*)alloc((size_t)N * 4);
    float* bufA = (float*)alloc((size_t)N * 128 * 4);
    float* bufB = (float*)alloc((size_t)N * 128 * 4);

    const int gE = cdiv(E, 256);
    const int gN = cdiv(N, 256);
    const int nb = gN;  // scan1 block count (391 <= 512)
    const int gT = cdiv(N, 64);  // tiled-gemm grid

    // --- CSR build ---
    zero_i32<<<gN, 256, 0, stream>>>(cnt, N);
    count_kernel<<<gE, 256, 0, stream>>>(dst, cnt, E);
    scan1<<<nb, 256, 0, stream>>>(cnt, off, bsum, N);
    scan2<<<1, 512, 0, stream>>>(bsum, bpre, nb, off, N, E);
    scan3<<<nb, 256, 0, stream>>>(cnt, bpre, off, cursor, N);
    fill_kernel<<<gE, 256, 0, stream>>>(src, dst, off, cursor, csr, E);
    dinv_kernel<<<gN, 256, 0, stream>>>(cnt, dinv, N);

    // --- Layer 1: [N,2] @ [2,128] ---
    gemm_small<2, 128><<<cdiv(N, 8), 256, 0, stream>>>(x, W1, bufA, N);
    agg_kernel<128><<<cdiv(N, 4), 256, 0, stream>>>(bufA, off, csr, dinv, b1, bufB, N);
    // --- Layer 2: [N,128] @ [128,128] ---
    gemm_tiled<128, 128><<<gT, 256, 0, stream>>>(bufB, W2, bufA, N);
    agg_kernel<128><<<cdiv(N, 4), 256, 0, stream>>>(bufA, off, csr, dinv, b2, bufB, N);
    // --- Layer 3: [N,128] @ [128,32] ---
    gemm_tiled<128, 32><<<gT, 256, 0, stream>>>(bufB, W3, bufA, N);
    agg_kernel<32><<<cdiv(N, 8), 256, 0, stream>>>(bufA, off, csr, dinv, b3, bufB, N);
    // --- Layer 4: [N,32] @ [32,32] ---
    gemm_tiled<32, 32><<<gT, 256, 0, stream>>>(bufB, W4, bufA, N);
    agg_kernel<32><<<cdiv(N, 8), 256, 0, stream>>>(bufA, off, csr, dinv, b4, bufB, N);
    // --- Layer 5: [N,32] @ [32,64] ---
    gemm_tiled<32, 64><<<gT, 256, 0, stream>>>(bufB, W5, bufA, N);
    agg_kernel<64><<<cdiv(N, 4), 256, 0, stream>>>(bufA, off, csr, dinv, b5, bufB, N);
    // --- Final linear: [N,64] @ [64,1] ---
    final_kernel<<<gN, 256, 0, stream>>>(bufB, Wl, bl, (float*)d_out, N);
}

// Round 4
// 638.920 us; speedup vs baseline: 3.4431x; 1.3224x over previous
//
#include <hip/hip_runtime.h>
#include <math.h>

// ---------------------------------------------------------------------------
// GCN 5-layer forward.
//   CSR by dst (count -> scan -> fill, fill also stores norm[e]=dinv[src]).
//   Per layer, exploit linearity  A_hat (X W) == (A_hat X) W  to aggregate on
//   the NARROW side:
//     L1: agg raw x [N,2]  -> gemm 2->128 (+bias+relu)
//     L2: gemm 128->128    -> agg<128>   (+bias+relu)
//     L3: gemm 128->32     -> agg<32>    (+bias+relu)
//     L4: gemm 32->32      -> agg<32>    (+bias+relu)
//     L5: agg<32> raw      -> gemm 32->64 (+bias+relu)
//     final [N,64] @ [64,1]
// R3: layer reorder (kills one agg<128>), norm[] precompute (no per-layer
//     random dinv gather), agg uses float4 / 2-edge unroll for more MLP.
// ---------------------------------------------------------------------------

static inline int cdiv(int a, int b) { return (a + b - 1) / b; }

__global__ void zero_i32(int* __restrict__ p, int n) {
    int i = blockIdx.x * 256 + threadIdx.x;
    if (i < n) p[i] = 0;
}

__global__ void count_kernel(const int* __restrict__ dst, int* __restrict__ cnt, int E) {
    int e = blockIdx.x * 256 + threadIdx.x;
    if (e < E) atomicAdd(&cnt[dst[e]], 1);
}

// Inclusive scan per 256-block; inclusive partials to off, block totals to bsum.
__global__ void scan1(const int* __restrict__ cnt, int* __restrict__ off,
                      int* __restrict__ bsum, int n) {
    __shared__ int sm[256];
    int i = blockIdx.x * 256 + threadIdx.x;
    int v = (i < n) ? cnt[i] : 0;
    sm[threadIdx.x] = v;
    __syncthreads();
    for (int ofs = 1; ofs < 256; ofs <<= 1) {
        int t = (threadIdx.x >= (unsigned)ofs) ? sm[threadIdx.x - ofs] : 0;
        __syncthreads();
        sm[threadIdx.x] += t;
        __syncthreads();
    }
    if (i < n) off[i] = sm[threadIdx.x];
    if (threadIdx.x == 255) bsum[blockIdx.x] = sm[255];
}

// Exclusive scan of block sums (nb <= 512).
__global__ void scan2(const int* __restrict__ bsum, int* __restrict__ bpre,
                      int nb, int* __restrict__ off, int N, int E) {
    __shared__ int sm[512];
    int t = threadIdx.x;
    sm[t] = (t < nb) ? bsum[t] : 0;
    __syncthreads();
    for (int ofs = 1; ofs < 512; ofs <<= 1) {
        int v = (t >= ofs) ? sm[t - ofs] : 0;
        __syncthreads();
        sm[t] += v;
        __syncthreads();
    }
    if (t < nb) bpre[t] = sm[t] - bsum[t];
    if (t == 0) off[N] = E;
}

__global__ void scan3(const int* __restrict__ cnt, const int* __restrict__ bpre,
                      int* __restrict__ off, int* __restrict__ cursor, int n) {
    int i = blockIdx.x * 256 + threadIdx.x;
    if (i < n) {
        off[i] = off[i] - cnt[i] + bpre[blockIdx.x];
        cursor[i] = 0;
    }
}

__global__ void dinv_kernel(const int* __restrict__ cnt, float* __restrict__ dinv, int n) {
    int i = blockIdx.x * 256 + threadIdx.x;
    if (i < n) dinv[i] = 1.0f / sqrtf((float)cnt[i] + 1.0f);
}

// Fill CSR; also store per-edge norm = dinv[src[e]] so agg never gathers dinv.
__global__ void fill_kernel(const int* __restrict__ src, const int* __restrict__ dst,
                            const int* __restrict__ off, int* __restrict__ cursor,
                            const float* __restrict__ dinv,
                            int* __restrict__ csr, float* __restrict__ normv, int E) {
    int e = blockIdx.x * 256 + threadIdx.x;
    if (e < E) {
        int d = dst[e];
        int s = src[e];
        int p = atomicAdd(&cursor[d], 1);
        int pos = off[d] + p;
        csr[pos] = s;
        normv[pos] = dinv[s];
    }
}

// ---------------------------------------------------------------------------
// Raw aggregation of the [N,2] input: one thread per node.
// out[v] = dinv[v]*sum(norm_e * x[src]) + x[v]*dinv[v]^2   (no bias/relu)
// ---------------------------------------------------------------------------
__global__ __launch_bounds__(256) void agg2_kernel(const float* __restrict__ x,
                                                   const int* __restrict__ off,
                                                   const int* __restrict__ csr,
                                                   const float* __restrict__ normv,
                                                   const float* __restrict__ dinv,
                                                   float* __restrict__ out, int n) {
    int v = blockIdx.x * 256 + threadIdx.x;
    if (v >= n) return;
    float a0 = 0.f, a1 = 0.f;
    int e0 = off[v], e1 = off[v + 1];
    for (int e = e0; e < e1; e++) {
        int s = csr[e];
        float w = normv[e];
        float2 xs = *reinterpret_cast<const float2*>(x + 2 * (size_t)s);
        a0 += w * xs.x;
        a1 += w * xs.y;
    }
    float dv = dinv[v], dv2 = dv * dv;
    float2 xv = *reinterpret_cast<const float2*>(x + 2 * (size_t)v);
    *reinterpret_cast<float2*>(out + 2 * (size_t)v) =
        float2{dv * a0 + xv.x * dv2, dv * a1 + xv.y * dv2};
}

// ---------------------------------------------------------------------------
// Aggregation, L lanes per node, CPL = F/L cols per lane (4 -> float4 loads,
// 2 -> float2). BR: fused bias+relu epilogue; else raw.
// ---------------------------------------------------------------------------
template <int F, int L, bool BR>
__global__ __launch_bounds__(256) void agg_kernel(const float* __restrict__ h,
                                                  const int* __restrict__ off,
                                                  const int* __restrict__ csr,
                                                  const float* __restrict__ normv,
                                                  const float* __restrict__ dinv,
                                                  const float* __restrict__ bias,
                                                  float* __restrict__ out, int n) {
    constexpr int CPL = F / L;             // 4 or 2
    constexpr int NPW = 64 / L;            // nodes per wave
    constexpr int NPB = 4 * NPW;           // nodes per block
    static_assert(CPL == 4 || CPL == 2, "CPL must be 2 or 4");

    int tid = threadIdx.x;
    int wave = tid >> 6;
    int lane = tid & 63;
    int sub = lane / L;
    int sl = lane % L;
    int v = blockIdx.x * NPB + wave * NPW + sub;
    if (v >= n) return;

    int start = off[v];
    int end = off[v + 1];
    int subbase = sub * L;

    float acc[CPL];
#pragma unroll
    for (int c = 0; c < CPL; c++) acc[c] = 0.f;

    for (int base = start; base < end; base += L) {
        int m = end - base;
        if (m > L) m = L;
        int idx = 0;
        float w = 0.f;
        if (sl < m) {
            idx = csr[base + sl];
            w = normv[base + sl];
        }
        int i = 0;
        for (; i + 1 < m; i += 2) {
            int s0 = __shfl(idx, subbase + i);
            int s1 = __shfl(idx, subbase + i + 1);
            float d0 = __shfl(w, subbase + i);
            float d1 = __shfl(w, subbase + i + 1);
            if constexpr (CPL == 4) {
                float4 h0 = *reinterpret_cast<const float4*>(h + (size_t)s0 * F + sl * 4);
                float4 h1 = *reinterpret_cast<const float4*>(h + (size_t)s1 * F + sl * 4);
                acc[0] += d0 * h0.x + d1 * h1.x;
                acc[1] += d0 * h0.y + d1 * h1.y;
                acc[2] += d0 * h0.z + d1 * h1.z;
                acc[3] += d0 * h0.w + d1 * h1.w;
            } else {
                float2 h0 = *reinterpret_cast<const float2*>(h + (size_t)s0 * F + sl * 2);
                float2 h1 = *reinterpret_cast<const float2*>(h + (size_t)s1 * F + sl * 2);
                acc[0] += d0 * h0.x + d1 * h1.x;
                acc[1] += d0 * h0.y + d1 * h1.y;
            }
        }
        if (i < m) {
            int s0 = __shfl(idx, subbase + i);
            float d0 = __shfl(w, subbase + i);
            if constexpr (CPL == 4) {
                float4 h0 = *reinterpret_cast<const float4*>(h + (size_t)s0 * F + sl * 4);
                acc[0] += d0 * h0.x;
                acc[1] += d0 * h0.y;
                acc[2] += d0 * h0.z;
                acc[3] += d0 * h0.w;
            } else {
                float2 h0 = *reinterpret_cast<const float2*>(h + (size_t)s0 * F + sl * 2);
                acc[0] += d0 * h0.x;
                acc[1] += d0 * h0.y;
            }
        }
    }

    float dv = dinv[v];
    float dv2 = dv * dv;
    if constexpr (CPL == 4) {
        float4 hv = *reinterpret_cast<const float4*>(h + (size_t)v * F + sl * 4);
        float o0 = dv * acc[0] + hv.x * dv2;
        float o1 = dv * acc[1] + hv.y * dv2;
        float o2 = dv * acc[2] + hv.z * dv2;
        float o3 = dv * acc[3] + hv.w * dv2;
        if constexpr (BR) {
            float4 b = *reinterpret_cast<const float4*>(bias + sl * 4);
            o0 = fmaxf(o0 + b.x, 0.f);
            o1 = fmaxf(o1 + b.y, 0.f);
            o2 = fmaxf(o2 + b.z, 0.f);
            o3 = fmaxf(o3 + b.w, 0.f);
        }
        *reinterpret_cast<float4*>(out + (size_t)v * F + sl * 4) = float4{o0, o1, o2, o3};
    } else {
        float2 hv = *reinterpret_cast<const float2*>(h + (size_t)v * F + sl * 2);
        float o0 = dv * acc[0] + hv.x * dv2;
        float o1 = dv * acc[1] + hv.y * dv2;
        if constexpr (BR) {
            float2 b = *reinterpret_cast<const float2*>(bias + sl * 2);
            o0 = fmaxf(o0 + b.x, 0.f);
            o1 = fmaxf(o1 + b.y, 0.f);
        }
        *reinterpret_cast<float2*>(out + (size_t)v * F + sl * 2) = float2{o0, o1};
    }
}

// ---------------------------------------------------------------------------
// Register-tiled GEMM: h[N,F] = x[N,K] @ W[K,F] (+bias, relu if BR).
// ---------------------------------------------------------------------------
template <int K, int F, bool BR>
__global__ __launch_bounds__(256, 4) void gemm_tiled(const float* __restrict__ x,
                                                     const float* __restrict__ W,
                                                     const float* __restrict__ bias,
                                                     float* __restrict__ h, int n) {
    constexpr int KC = 16;
    constexpr int KCP = 20;             // padded row stride (80 B, 16B-aligned)
    constexpr int ROWS = 64;
    constexpr int TPC = F / 4;
    constexpr int RT = 256 / TPC;
    constexpr int RPT = ROWS / RT;
    static_assert(K % KC == 0, "K must be a multiple of 16");

    __shared__ float Ws[KC * F];
    __shared__ float Xs[ROWS * KCP];

    const int tid = threadIdx.x;
    const int cb = (tid % TPC) * 4;
    const int tr = tid / TPC;
    const int row0 = blockIdx.x * ROWS;

    float acc[RPT][4];
#pragma unroll
    for (int r = 0; r < RPT; r++)
#pragma unroll
        for (int j = 0; j < 4; j++) acc[r][j] = 0.f;

#pragma unroll 1
    for (int k0 = 0; k0 < K; k0 += KC) {
        __syncthreads();
        {
            int r = tid >> 2;
            int kk = (tid & 3) * 4;
            int gr = row0 + r;
            float4 v = (gr < n)
                ? *reinterpret_cast<const float4*>(x + (size_t)gr * K + k0 + kk)
                : float4{0.f, 0.f, 0.f, 0.f};
            *reinterpret_cast<float4*>(&Xs[r * KCP + kk]) = v;
        }
        for (int i = tid; i < KC * F / 4; i += 256) {
            *reinterpret_cast<float4*>(&Ws[i * 4]) =
                *reinterpret_cast<const float4*>(W + (size_t)k0 * F + i * 4);
        }
        __syncthreads();

#pragma unroll
        for (int kk4 = 0; kk4 < KC; kk4 += 4) {
            float4 xr[RPT];
#pragma unroll
            for (int r = 0; r < RPT; r++)
                xr[r] = *reinterpret_cast<const float4*>(&Xs[(tr * RPT + r) * KCP + kk4]);
#pragma unroll
            for (int j = 0; j < 4; j++) {
                float4 w = *reinterpret_cast<const float4*>(&Ws[(kk4 + j) * F + cb]);
#pragma unroll
                for (int r = 0; r < RPT; r++) {
                    float xv = (j == 0) ? xr[r].x : (j == 1) ? xr[r].y
                             : (j == 2) ? xr[r].z : xr[r].w;
                    acc[r][0] += xv * w.x;
                    acc[r][1] += xv * w.y;
                    acc[r][2] += xv * w.z;
                    acc[r][3] += xv * w.w;
                }
            }
        }
    }

    float4 b = float4{0.f, 0.f, 0.f, 0.f};
    if constexpr (BR) b = *reinterpret_cast<const float4*>(bias + cb);
#pragma unroll
    for (int r = 0; r < RPT; r++) {
        int row = row0 + tr * RPT + r;
        if (row < n) {
            float o0 = acc[r][0], o1 = acc[r][1], o2 = acc[r][2], o3 = acc[r][3];
            if constexpr (BR) {
                o0 = fmaxf(o0 + b.x, 0.f);
                o1 = fmaxf(o1 + b.y, 0.f);
                o2 = fmaxf(o2 + b.z, 0.f);
                o3 = fmaxf(o3 + b.w, 0.f);
            }
            *reinterpret_cast<float4*>(&h[(size_t)row * F + cb]) = float4{o0, o1, o2, o3};
        }
    }
}

// Simple GEMM for K=2 (layer 1), optional bias+relu.
template <int K, int F, bool BR>
__global__ __launch_bounds__(256, 4) void gemm_small(const float* __restrict__ x,
                                                     const float* __restrict__ W,
                                                     const float* __restrict__ bias,
                                                     float* __restrict__ h, int n) {
    constexpr int TPR = F / 4;
    constexpr int ROWS = 256 / TPR;
    __shared__ float Ws[K * F];
    for (int i = threadIdx.x; i < K * F; i += 256) Ws[i] = W[i];
    __syncthreads();

    int tid = threadIdx.x;
    int cb = (tid % TPR) * 4;
    int r = blockIdx.x * ROWS + tid / TPR;
    if (r >= n) return;

    const float* xr = x + (size_t)r * K;
    float a0 = 0.f, a1 = 0.f, a2 = 0.f, a3 = 0.f;
#pragma unroll
    for (int k = 0; k < K; k++) {
        float xv = xr[k];
        float4 w = *reinterpret_cast<const float4*>(&Ws[k * F + cb]);
        a0 += xv * w.x; a1 += xv * w.y; a2 += xv * w.z; a3 += xv * w.w;
    }
    if constexpr (BR) {
        float4 b = *reinterpret_cast<const float4*>(bias + cb);
        a0 = fmaxf(a0 + b.x, 0.f);
        a1 = fmaxf(a1 + b.y, 0.f);
        a2 = fmaxf(a2 + b.z, 0.f);
        a3 = fmaxf(a3 + b.w, 0.f);
    }
    *reinterpret_cast<float4*>(&h[(size_t)r * F + cb]) = float4{a0, a1, a2, a3};
}

// Final linear: out[v] = x[v,:64] . Wl + bl
__global__ __launch_bounds__(256) void final_kernel(const float* __restrict__ x,
                                                    const float* __restrict__ Wl,
                                                    const float* __restrict__ bl,
                                                    float* __restrict__ out, int n) {
    __shared__ float w[64];
    if (threadIdx.x < 64) w[threadIdx.x] = Wl[threadIdx.x];
    __syncthreads();
    int i = blockIdx.x * 256 + threadIdx.x;
    if (i >= n) return;
    const float* r = x + (size_t)i * 64;
    float acc = 0.f;
#pragma unroll
    for (int k = 0; k < 64; k += 4) {
        float4 xv = *reinterpret_cast<const float4*>(r + k);
        acc += xv.x * w[k] + xv.y * w[k + 1] + xv.z * w[k + 2] + xv.w * w[k + 3];
    }
    out[i] = acc + bl[0];
}

extern "C" void kernel_launch(void* const* d_in, const int* in_sizes, int n_in,
                              void* d_out, int out_size, void* d_ws, size_t ws_size,
                              hipStream_t stream) {
    const float* x = (const float*)d_in[0];
    const int* ei = (const int*)d_in[1];
    const float* W1 = (const float*)d_in[3];
    const float* b1 = (const float*)d_in[4];
    const float* W2 = (const float*)d_in[5];
    const float* b2 = (const float*)d_in[6];
    const float* W3 = (const float*)d_in[7];
    const float* b3 = (const float*)d_in[8];
    const float* W4 = (const float*)d_in[9];
    const float* b4 = (const float*)d_in[10];
    const float* W5 = (const float*)d_in[11];
    const float* b5 = (const float*)d_in[12];
    const float* Wl = (const float*)d_in[13];
    const float* bl = (const float*)d_in[14];

    const int N = in_sizes[0] / 2;
    const int E = in_sizes[1] / 2;
    const int* src = ei;
    const int* dst = ei + E;

    char* wp = (char*)d_ws;
    auto alloc = [&](size_t bytes) -> void* {
        void* p = wp;
        wp += ((bytes + 255) / 256) * 256;
        return p;
    };
    int* cnt = (int*)alloc((size_t)N * 4);
    int* off = (int*)alloc((size_t)(N + 1) * 4);
    int* cursor = (int*)alloc((size_t)N * 4);
    int* bsum = (int*)alloc(512 * 4);
    int* bpre = (int*)alloc(512 * 4);
    int* csr = (int*)alloc((size_t)E * 4);
    float* normv = (float*)alloc((size_t)E * 4);
    float* dinv = (float*)alloc((size_t)N * 4);
    float* t2 = (float*)alloc((size_t)N * 2 * 4);
    float* bufA = (float*)alloc((size_t)N * 128 * 4);
    float* bufB = (float*)alloc((size_t)N * 128 * 4);

    const int gE = cdiv(E, 256);
    const int gN = cdiv(N, 256);
    const int nb = gN;
    const int gT = cdiv(N, 64);

    // --- CSR build (+ per-edge norm) ---
    zero_i32<<<gN, 256, 0, stream>>>(cnt, N);
    count_kernel<<<gE, 256, 0, stream>>>(dst, cnt, E);
    scan1<<<nb, 256, 0, stream>>>(cnt, off, bsum, N);
    scan2<<<1, 512, 0, stream>>>(bsum, bpre, nb, off, N, E);
    scan3<<<nb, 256, 0, stream>>>(cnt, bpre, off, cursor, N);
    dinv_kernel<<<gN, 256, 0, stream>>>(cnt, dinv, N);
    fill_kernel<<<gE, 256, 0, stream>>>(src, dst, off, cursor, dinv, csr, normv, E);

    // --- Layer 1: agg raw [N,2], then GEMM 2->128 (+b1, relu) ---
    agg2_kernel<<<gN, 256, 0, stream>>>(x, off, csr, normv, dinv, t2, N);
    gemm_small<2, 128, true><<<cdiv(N, 8), 256, 0, stream>>>(t2, W1, b1, bufA, N);
    // --- Layer 2: GEMM 128->128, agg<128> (+b2, relu) ---
    gemm_tiled<128, 128, false><<<gT, 256, 0, stream>>>(bufA, W2, nullptr, bufB, N);
    agg_kernel<128, 32, true><<<cdiv(N, 8), 256, 0, stream>>>(bufB, off, csr, normv, dinv, b2, bufA, N);
    // --- Layer 3: GEMM 128->32, agg<32> (+b3, relu) ---
    gemm_tiled<128, 32, false><<<gT, 256, 0, stream>>>(bufA, W3, nullptr, bufB, N);
    agg_kernel<32, 16, true><<<cdiv(N, 16), 256, 0, stream>>>(bufB, off, csr, normv, dinv, b3, bufA, N);
    // --- Layer 4: GEMM 32->32, agg<32> (+b4, relu) ---
    gemm_tiled<32, 32, false><<<gT, 256, 0, stream>>>(bufA, W4, nullptr, bufB, N);
    agg_kernel<32, 16, true><<<cdiv(N, 16), 256, 0, stream>>>(bufB, off, csr, normv, dinv, b4, bufA, N);
    // --- Layer 5: agg<32> raw, then GEMM 32->64 (+b5, relu) ---
    agg_kernel<32, 16, false><<<cdiv(N, 16), 256, 0, stream>>>(bufA, off, csr, normv, dinv, nullptr, bufB, N);
    gemm_tiled<32, 64, true><<<gT, 256, 0, stream>>>(bufB, W5, b5, bufA, N);
    // --- Final linear ---
    final_kernel<<<gN, 256, 0, stream>>>(bufA, Wl, bl, (float*)d_out, N);
}

// Round 5
// 589.700 us; speedup vs baseline: 3.7305x; 1.0835x over previous
//
#include <hip/hip_runtime.h>
#include <math.h>

// ---------------------------------------------------------------------------
// GCN 5-layer forward, dinv-prescaled formulation.
//   A_hat = D^-1/2 A D^-1/2. Keep tensors pre-scaled: hs = dinv (.) h.
//   Since (dinv (.) h) @ W = dinv (.) (h @ W), GEMM outputs of pre-scaled
//   inputs are already pre-scaled. Aggregation needs no per-edge weight:
//     agg[v] = dinv[v] * ( sum_{s in N(v)} hs[s] + hs[v] )
//   so the CSR carries ONLY src indices (fill = one 4-B scatter per edge,
//   was two -> halves write-allocate line traffic, R4's 155 MB WRITE_SIZE).
// Layer plan (narrow-side aggregation):
//   dinv_xs: dinv[v], xs = dinv*x [N,2]
//   L1: agg2(xs) -> t2 = A_hat x ; gemm 2->128 +b1 relu, *dinv  -> h1s
//   L2: gemm 128->128 (h1s@W2 = pre-scaled) ; agg<128> +b2 relu *dinv -> x2s
//   L3: gemm 128->32 ; agg<32> +b3 relu *dinv -> x3s
//   L4: gemm 32->32  ; agg<32> +b4 relu *dinv -> x4s
//   L5: agg<32> raw -> A_hat x4 ; gemm 32->64 +b5 relu -> x5
//   final [N,64]@[64,1]
// R5: normv deleted (fill & aggs slim), agg<32> uses 8 lanes x float4.
// ---------------------------------------------------------------------------

static inline int cdiv(int a, int b) { return (a + b - 1) / b; }

__global__ void zero_i32(int* __restrict__ p, int n) {
    int i = blockIdx.x * 256 + threadIdx.x;
    if (i < n) p[i] = 0;
}

__global__ void count_kernel(const int* __restrict__ dst, int* __restrict__ cnt, int E) {
    int e = blockIdx.x * 256 + threadIdx.x;
    if (e < E) atomicAdd(&cnt[dst[e]], 1);
}

// Inclusive scan per 256-block; inclusive partials to off, block totals to bsum.
__global__ void scan1(const int* __restrict__ cnt, int* __restrict__ off,
                      int* __restrict__ bsum, int n) {
    __shared__ int sm[256];
    int i = blockIdx.x * 256 + threadIdx.x;
    int v = (i < n) ? cnt[i] : 0;
    sm[threadIdx.x] = v;
    __syncthreads();
    for (int ofs = 1; ofs < 256; ofs <<= 1) {
        int t = (threadIdx.x >= (unsigned)ofs) ? sm[threadIdx.x - ofs] : 0;
        __syncthreads();
        sm[threadIdx.x] += t;
        __syncthreads();
    }
    if (i < n) off[i] = sm[threadIdx.x];
    if (threadIdx.x == 255) bsum[blockIdx.x] = sm[255];
}

// Exclusive scan of block sums (nb <= 512).
__global__ void scan2(const int* __restrict__ bsum, int* __restrict__ bpre,
                      int nb, int* __restrict__ off, int N, int E) {
    __shared__ int sm[512];
    int t = threadIdx.x;
    sm[t] = (t < nb) ? bsum[t] : 0;
    __syncthreads();
    for (int ofs = 1; ofs < 512; ofs <<= 1) {
        int v = (t >= ofs) ? sm[t - ofs] : 0;
        __syncthreads();
        sm[t] += v;
        __syncthreads();
    }
    if (t < nb) bpre[t] = sm[t] - bsum[t];
    if (t == 0) off[N] = E;
}

__global__ void scan3(const int* __restrict__ cnt, const int* __restrict__ bpre,
                      int* __restrict__ off, int* __restrict__ cursor, int n) {
    int i = blockIdx.x * 256 + threadIdx.x;
    if (i < n) {
        off[i] = off[i] - cnt[i] + bpre[blockIdx.x];
        cursor[i] = 0;
    }
}

// dinv[v] = 1/sqrt(deg+1); xs[v] = dinv[v] * x[v]  (pre-scaled layer-1 input)
__global__ void dinv_xs_kernel(const int* __restrict__ cnt, const float* __restrict__ x,
                               float* __restrict__ dinv, float* __restrict__ xs, int n) {
    int i = blockIdx.x * 256 + threadIdx.x;
    if (i < n) {
        float dv = 1.0f / sqrtf((float)cnt[i] + 1.0f);
        dinv[i] = dv;
        float2 xv = *reinterpret_cast<const float2*>(x + 2 * (size_t)i);
        *reinterpret_cast<float2*>(xs + 2 * (size_t)i) = float2{dv * xv.x, dv * xv.y};
    }
}

// Fill CSR (src indices only).
__global__ void fill_kernel(const int* __restrict__ src, const int* __restrict__ dst,
                            const int* __restrict__ off, int* __restrict__ cursor,
                            int* __restrict__ csr, int E) {
    int e = blockIdx.x * 256 + threadIdx.x;
    if (e < E) {
        int d = dst[e];
        int p = atomicAdd(&cursor[d], 1);
        csr[off[d] + p] = src[e];
    }
}

// ---------------------------------------------------------------------------
// Aggregation of pre-scaled [N,2] input: one thread per node.
// t2[v] = dinv[v] * (sum_s xs[s] + xs[v])   == (A_hat x)[v]
// ---------------------------------------------------------------------------
__global__ __launch_bounds__(256) void agg2_kernel(const float* __restrict__ xs,
                                                   const int* __restrict__ off,
                                                   const int* __restrict__ csr,
                                                   const float* __restrict__ dinv,
                                                   float* __restrict__ out, int n) {
    int v = blockIdx.x * 256 + threadIdx.x;
    if (v >= n) return;
    float a0 = 0.f, a1 = 0.f;
    int e0 = off[v], e1 = off[v + 1];
    for (int e = e0; e < e1; e++) {
        int s = csr[e];
        float2 q = *reinterpret_cast<const float2*>(xs + 2 * (size_t)s);
        a0 += q.x;
        a1 += q.y;
    }
    float dv = dinv[v];
    float2 xv = *reinterpret_cast<const float2*>(xs + 2 * (size_t)v);
    *reinterpret_cast<float2*>(out + 2 * (size_t)v) =
        float2{dv * (a0 + xv.x), dv * (a1 + xv.y)};
}

// ---------------------------------------------------------------------------
// Aggregation of pre-scaled h: L lanes/node, each lane owns 4 consecutive
// cols (float4). out[v] = post(dinv[v] * (sum_s h[s] + h[v]))
//   BR: + bias, relu.   PS: multiply by dinv[v] again (pre-scale for next agg)
// ---------------------------------------------------------------------------
template <int F, int L, bool BR, bool PS>
__global__ __launch_bounds__(256) void agg_kernel(const float* __restrict__ h,
                                                  const int* __restrict__ off,
                                                  const int* __restrict__ csr,
                                                  const float* __restrict__ dinv,
                                                  const float* __restrict__ bias,
                                                  float* __restrict__ out, int n) {
    static_assert(F == 4 * L, "each lane owns 4 cols");
    constexpr int NPW = 64 / L;            // nodes per wave
    constexpr int NPB = 4 * NPW;           // nodes per block

    int tid = threadIdx.x;
    int wave = tid >> 6;
    int lane = tid & 63;
    int sub = lane / L;
    int sl = lane % L;
    int v = blockIdx.x * NPB + wave * NPW + sub;
    if (v >= n) return;

    int start = off[v];
    int end = off[v + 1];
    int subbase = sub * L;

    float a0 = 0.f, a1 = 0.f, a2 = 0.f, a3 = 0.f;

    for (int base = start; base < end; base += L) {
        int m = end - base;
        if (m > L) m = L;
        int idx = (sl < m) ? csr[base + sl] : 0;
        int i = 0;
        for (; i + 1 < m; i += 2) {
            int s0 = __shfl(idx, subbase + i);
            int s1 = __shfl(idx, subbase + i + 1);
            float4 h0 = *reinterpret_cast<const float4*>(h + (size_t)s0 * F + sl * 4);
            float4 h1 = *reinterpret_cast<const float4*>(h + (size_t)s1 * F + sl * 4);
            a0 += h0.x + h1.x;
            a1 += h0.y + h1.y;
            a2 += h0.z + h1.z;
            a3 += h0.w + h1.w;
        }
        if (i < m) {
            int s0 = __shfl(idx, subbase + i);
            float4 h0 = *reinterpret_cast<const float4*>(h + (size_t)s0 * F + sl * 4);
            a0 += h0.x;
            a1 += h0.y;
            a2 += h0.z;
            a3 += h0.w;
        }
    }

    float dv = dinv[v];
    float4 hv = *reinterpret_cast<const float4*>(h + (size_t)v * F + sl * 4);
    float o0 = dv * (a0 + hv.x);
    float o1 = dv * (a1 + hv.y);
    float o2 = dv * (a2 + hv.z);
    float o3 = dv * (a3 + hv.w);
    if constexpr (BR) {
        float4 b = *reinterpret_cast<const float4*>(bias + sl * 4);
        o0 = fmaxf(o0 + b.x, 0.f);
        o1 = fmaxf(o1 + b.y, 0.f);
        o2 = fmaxf(o2 + b.z, 0.f);
        o3 = fmaxf(o3 + b.w, 0.f);
    }
    if constexpr (PS) {
        o0 *= dv; o1 *= dv; o2 *= dv; o3 *= dv;
    }
    *reinterpret_cast<float4*>(out + (size_t)v * F + sl * 4) = float4{o0, o1, o2, o3};
}

// ---------------------------------------------------------------------------
// Register-tiled GEMM: h[N,F] = x[N,K] @ W[K,F]; epilogue +bias/relu (BR),
// *dinv[row] (PS).
// ---------------------------------------------------------------------------
template <int K, int F, bool BR, bool PS>
__global__ __launch_bounds__(256, 4) void gemm_tiled(const float* __restrict__ x,
                                                     const float* __restrict__ W,
                                                     const float* __restrict__ bias,
                                                     const float* __restrict__ dinv,
                                                     float* __restrict__ h, int n) {
    constexpr int KC = 16;
    constexpr int KCP = 20;             // padded row stride (80 B, 16B-aligned)
    constexpr int ROWS = 64;
    constexpr int TPC = F / 4;
    constexpr int RT = 256 / TPC;
    constexpr int RPT = ROWS / RT;
    static_assert(K % KC == 0, "K must be a multiple of 16");

    __shared__ float Ws[KC * F];
    __shared__ float Xs[ROWS * KCP];

    const int tid = threadIdx.x;
    const int cb = (tid % TPC) * 4;
    const int tr = tid / TPC;
    const int row0 = blockIdx.x * ROWS;

    float acc[RPT][4];
#pragma unroll
    for (int r = 0; r < RPT; r++)
#pragma unroll
        for (int j = 0; j < 4; j++) acc[r][j] = 0.f;

#pragma unroll 1
    for (int k0 = 0; k0 < K; k0 += KC) {
        __syncthreads();
        {
            int r = tid >> 2;
            int kk = (tid & 3) * 4;
            int gr = row0 + r;
            float4 v = (gr < n)
                ? *reinterpret_cast<const float4*>(x + (size_t)gr * K + k0 + kk)
                : float4{0.f, 0.f, 0.f, 0.f};
            *reinterpret_cast<float4*>(&Xs[r * KCP + kk]) = v;
        }
        for (int i = tid; i < KC * F / 4; i += 256) {
            *reinterpret_cast<float4*>(&Ws[i * 4]) =
                *reinterpret_cast<const float4*>(W + (size_t)k0 * F + i * 4);
        }
        __syncthreads();

#pragma unroll
        for (int kk4 = 0; kk4 < KC; kk4 += 4) {
            float4 xr[RPT];
#pragma unroll
            for (int r = 0; r < RPT; r++)
                xr[r] = *reinterpret_cast<const float4*>(&Xs[(tr * RPT + r) * KCP + kk4]);
#pragma unroll
            for (int j = 0; j < 4; j++) {
                float4 w = *reinterpret_cast<const float4*>(&Ws[(kk4 + j) * F + cb]);
#pragma unroll
                for (int r = 0; r < RPT; r++) {
                    float xv = (j == 0) ? xr[r].x : (j == 1) ? xr[r].y
                             : (j == 2) ? xr[r].z : xr[r].w;
                    acc[r][0] += xv * w.x;
                    acc[r][1] += xv * w.y;
                    acc[r][2] += xv * w.z;
                    acc[r][3] += xv * w.w;
                }
            }
        }
    }

    float4 b = float4{0.f, 0.f, 0.f, 0.f};
    if constexpr (BR) b = *reinterpret_cast<const float4*>(bias + cb);
#pragma unroll
    for (int r = 0; r < RPT; r++) {
        int row = row0 + tr * RPT + r;
        if (row < n) {
            float o0 = acc[r][0], o1 = acc[r][1], o2 = acc[r][2], o3 = acc[r][3];
            if constexpr (BR) {
                o0 = fmaxf(o0 + b.x, 0.f);
                o1 = fmaxf(o1 + b.y, 0.f);
                o2 = fmaxf(o2 + b.z, 0.f);
                o3 = fmaxf(o3 + b.w, 0.f);
            }
            if constexpr (PS) {
                float dv = dinv[row];
                o0 *= dv; o1 *= dv; o2 *= dv; o3 *= dv;
            }
            *reinterpret_cast<float4*>(&h[(size_t)row * F + cb]) = float4{o0, o1, o2, o3};
        }
    }
}

// Simple GEMM for K=2 (layer 1), epilogue +bias/relu (BR), *dinv (PS).
template <int K, int F, bool BR, bool PS>
__global__ __launch_bounds__(256, 4) void gemm_small(const float* __restrict__ x,
                                                     const float* __restrict__ W,
                                                     const float* __restrict__ bias,
                                                     const float* __restrict__ dinv,
                                                     float* __restrict__ h, int n) {
    constexpr int TPR = F / 4;
    constexpr int ROWS = 256 / TPR;
    __shared__ float Ws[K * F];
    for (int i = threadIdx.x; i < K * F; i += 256) Ws[i] = W[i];
    __syncthreads();

    int tid = threadIdx.x;
    int cb = (tid % TPR) * 4;
    int r = blockIdx.x * ROWS + tid / TPR;
    if (r >= n) return;

    const float* xr = x + (size_t)r * K;
    float a0 = 0.f, a1 = 0.f, a2 = 0.f, a3 = 0.f;
#pragma unroll
    for (int k = 0; k < K; k++) {
        float xv = xr[k];
        float4 w = *reinterpret_cast<const float4*>(&Ws[k * F + cb]);
        a0 += xv * w.x; a1 += xv * w.y; a2 += xv * w.z; a3 += xv * w.w;
    }
    if constexpr (BR) {
        float4 b = *reinterpret_cast<const float4*>(bias + cb);
        a0 = fmaxf(a0 + b.x, 0.f);
        a1 = fmaxf(a1 + b.y, 0.f);
        a2 = fmaxf(a2 + b.z, 0.f);
        a3 = fmaxf(a3 + b.w, 0.f);
    }
    if constexpr (PS) {
        float dv = dinv[r];
        a0 *= dv; a1 *= dv; a2 *= dv; a3 *= dv;
    }
    *reinterpret_cast<float4*>(&h[(size_t)r * F + cb]) = float4{a0, a1, a2, a3};
}

// Final linear: out[v] = x[v,:64] . Wl + bl
__global__ __launch_bounds__(256) void final_kernel(const float* __restrict__ x,
                                                    const float* __restrict__ Wl,
                                                    const float* __restrict__ bl,
                                                    float* __restrict__ out, int n) {
    __shared__ float w[64];
    if (threadIdx.x < 64) w[threadIdx.x] = Wl[threadIdx.x];
    __syncthreads();
    int i = blockIdx.x * 256 + threadIdx.x;
    if (i >= n) return;
    const float* r = x + (size_t)i * 64;
    float acc = 0.f;
#pragma unroll
    for (int k = 0; k < 64; k += 4) {
        float4 xv = *reinterpret_cast<const float4*>(r + k);
        acc += xv.x * w[k] + xv.y * w[k + 1] + xv.z * w[k + 2] + xv.w * w[k + 3];
    }
    out[i] = acc + bl[0];
}

extern "C" void kernel_launch(void* const* d_in, const int* in_sizes, int n_in,
                              void* d_out, int out_size, void* d_ws, size_t ws_size,
                              hipStream_t stream) {
    const float* x = (const float*)d_in[0];
    const int* ei = (const int*)d_in[1];
    const float* W1 = (const float*)d_in[3];
    const float* b1 = (const float*)d_in[4];
    const float* W2 = (const float*)d_in[5];
    const float* b2 = (const float*)d_in[6];
    const float* W3 = (const float*)d_in[7];
    const float* b3 = (const float*)d_in[8];
    const float* W4 = (const float*)d_in[9];
    const float* b4 = (const float*)d_in[10];
    const float* W5 = (const float*)d_in[11];
    const float* b5 = (const float*)d_in[12];
    const float* Wl = (const float*)d_in[13];
    const float* bl = (const float*)d_in[14];

    const int N = in_sizes[0] / 2;
    const int E = in_sizes[1] / 2;
    const int* src = ei;
    const int* dst = ei + E;

    char* wp = (char*)d_ws;
    auto alloc = [&](size_t bytes) -> void* {
        void* p = wp;
        wp += ((bytes + 255) / 256) * 256;
        return p;
    };
    int* cnt = (int*)alloc((size_t)N * 4);
    int* off = (int*)alloc((size_t)(N + 1) * 4);
    int* cursor = (int*)alloc((size_t)N * 4);
    int* bsum = (int*)alloc(512 * 4);
    int* bpre = (int*)alloc(512 * 4);
    int* csr = (int*)alloc((size_t)E * 4);
    float* dinv = (float*)alloc((size_t)N * 4);
    float* xs2 = (float*)alloc((size_t)N * 2 * 4);
    float* t2 = (float*)alloc((size_t)N * 2 * 4);
    float* bufA = (float*)alloc((size_t)N * 128 * 4);
    float* bufB = (float*)alloc((size_t)N * 128 * 4);

    const int gE = cdiv(E, 256);
    const int gN = cdiv(N, 256);
    const int nb = gN;
    const int gT = cdiv(N, 64);

    // --- CSR build ---
    zero_i32<<<gN, 256, 0, stream>>>(cnt, N);
    count_kernel<<<gE, 256, 0, stream>>>(dst, cnt, E);
    scan1<<<nb, 256, 0, stream>>>(cnt, off, bsum, N);
    scan2<<<1, 512, 0, stream>>>(bsum, bpre, nb, off, N, E);
    scan3<<<nb, 256, 0, stream>>>(cnt, bpre, off, cursor, N);
    dinv_xs_kernel<<<gN, 256, 0, stream>>>(cnt, x, dinv, xs2, N);
    fill_kernel<<<gE, 256, 0, stream>>>(src, dst, off, cursor, csr, E);

    // --- Layer 1: agg pre-scaled [N,2], gemm 2->128 (+b1, relu, *dinv) ---
    agg2_kernel<<<gN, 256, 0, stream>>>(xs2, off, csr, dinv, t2, N);
    gemm_small<2, 128, true, true><<<cdiv(N, 8), 256, 0, stream>>>(t2, W1, b1, dinv, bufA, N);
    // --- Layer 2: gemm 128->128 (raw), agg<128> (+b2, relu, *dinv) ---
    gemm_tiled<128, 128, false, false><<<gT, 256, 0, stream>>>(bufA, W2, nullptr, nullptr, bufB, N);
    agg_kernel<128, 32, true, true><<<cdiv(N, 8), 256, 0, stream>>>(bufB, off, csr, dinv, b2, bufA, N);
    // --- Layer 3: gemm 128->32, agg<32> (+b3, relu, *dinv) ---
    gemm_tiled<128, 32, false, false><<<gT, 256, 0, stream>>>(bufA, W3, nullptr, nullptr, bufB, N);
    agg_kernel<32, 8, true, true><<<cdiv(N, 32), 256, 0, stream>>>(bufB, off, csr, dinv, b3, bufA, N);
    // --- Layer 4: gemm 32->32, agg<32> (+b4, relu, *dinv) ---
    gemm_tiled<32, 32, false, false><<<gT, 256, 0, stream>>>(bufA, W4, nullptr, nullptr, bufB, N);
    agg_kernel<32, 8, true, true><<<cdiv(N, 32), 256, 0, stream>>>(bufB, off, csr, dinv, b4, bufA, N);
    // --- Layer 5: agg<32> raw -> A_hat x4, gemm 32->64 (+b5, relu) ---
    agg_kernel<32, 8, false, false><<<cdiv(N, 32), 256, 0, stream>>>(bufA, off, csr, dinv, nullptr, bufB, N);
    gemm_tiled<32, 64, true, false><<<gT, 256, 0, stream>>>(bufB, W5, b5, nullptr, bufA, N);
    // --- Final linear ---
    final_kernel<<<gN, 256, 0, stream>>>(bufA, Wl, bl, (float*)d_out, N);
}